// Round 2
// baseline (6997.661 us; speedup 1.0000x reference)
//
#include <hip/hip_runtime.h>
#include <math.h>

#define B_ROWS 65536
#define D_IN   784
#define D_HID  512
#define D_LAT  256
#define N_CODES 256

#define BM 64
#define BN 64
#define BK 16

// ---------------- f32 GEMM (decoder path) ----------------
// C[M,N] = act(A[M,K] @ W[K,N] + bias), optional fused sum((C - X)^2) into loss_acc.
// ACT: 0=none, 1=relu, 2=tanh
template<int ACT, bool FUSE_LOSS>
__global__ __launch_bounds__(256)
void gemm_kernel(const float* __restrict__ A, const float* __restrict__ W,
                 const float* __restrict__ bias, float* __restrict__ C,
                 const float* __restrict__ X, float* __restrict__ loss_acc,
                 int M, int N, int K)
{
    __shared__ float As[BK][BM + 4];
    __shared__ float Bs[BK][BN + 4];
    __shared__ float wsum[4];

    const int tid  = threadIdx.x;
    const int row0 = blockIdx.y * BM;
    const int col0 = blockIdx.x * BN;
    const int tx = tid & 15;
    const int ty = tid >> 4;

    const int a_r = tid >> 2;
    const int a_c = (tid & 3) << 2;
    const int b_r = tid >> 4;
    const int b_c = (tid & 15) << 2;

    float acc[4][4] = {};

    for (int k0 = 0; k0 < K; k0 += BK) {
        const float4 av = *(const float4*)(A + (size_t)(row0 + a_r) * K + (k0 + a_c));
        As[a_c + 0][a_r] = av.x;
        As[a_c + 1][a_r] = av.y;
        As[a_c + 2][a_r] = av.z;
        As[a_c + 3][a_r] = av.w;

        const int gc = col0 + b_c;
        float4 bv;
        if (gc + 3 < N) {
            bv = *(const float4*)(W + (size_t)(k0 + b_r) * N + gc);
        } else {
            bv.x = (gc + 0 < N) ? W[(size_t)(k0 + b_r) * N + gc + 0] : 0.f;
            bv.y = (gc + 1 < N) ? W[(size_t)(k0 + b_r) * N + gc + 1] : 0.f;
            bv.z = (gc + 2 < N) ? W[(size_t)(k0 + b_r) * N + gc + 2] : 0.f;
            bv.w = (gc + 3 < N) ? W[(size_t)(k0 + b_r) * N + gc + 3] : 0.f;
        }
        *(float4*)&Bs[b_r][b_c] = bv;

        __syncthreads();
        #pragma unroll
        for (int kk = 0; kk < BK; ++kk) {
            const float4 a = *(const float4*)&As[kk][ty << 2];
            const float4 b = *(const float4*)&Bs[kk][tx << 2];
            const float ar[4] = {a.x, a.y, a.z, a.w};
            const float br[4] = {b.x, b.y, b.z, b.w};
            #pragma unroll
            for (int i = 0; i < 4; ++i)
                #pragma unroll
                for (int j = 0; j < 4; ++j)
                    acc[i][j] = fmaf(ar[i], br[j], acc[i][j]);
        }
        __syncthreads();
    }

    float lsum = 0.f;
    #pragma unroll
    for (int i = 0; i < 4; ++i) {
        const int r = row0 + (ty << 2) + i;
        #pragma unroll
        for (int j = 0; j < 4; ++j) {
            const int c = col0 + (tx << 2) + j;
            if (c < N) {
                float v = acc[i][j] + bias[c];
                if (ACT == 1) v = fmaxf(v, 0.f);
                if (ACT == 2) v = tanhf(v);
                C[(size_t)r * N + c] = v;
                if (FUSE_LOSS) {
                    const float d = v - X[(size_t)r * N + c];
                    lsum = fmaf(d, d, lsum);
                }
            }
        }
    }

    if (FUSE_LOSS) {
        #pragma unroll
        for (int off = 32; off > 0; off >>= 1)
            lsum += __shfl_xor(lsum, off, 64);
        if ((tid & 63) == 0) wsum[tid >> 6] = lsum;
        __syncthreads();
        if (tid == 0)
            atomicAdd(loss_acc, wsum[0] + wsum[1] + wsum[2] + wsum[3]);
    }
}

// ---------------- f64-accumulate GEMM (encoder path) ----------------
// Same tiling, double accumulators: enc must be accurate to ~1e-9 so the VQ
// argmin matches the high-precision reference (gap scale ~0.04, see journal).
template<int ACT>
__global__ __launch_bounds__(256)
void gemm_f64_kernel(const float* __restrict__ A, const float* __restrict__ W,
                     const float* __restrict__ bias, float* __restrict__ C,
                     int M, int N, int K)
{
    __shared__ float As[BK][BM + 4];
    __shared__ float Bs[BK][BN + 4];

    const int tid  = threadIdx.x;
    const int row0 = blockIdx.y * BM;
    const int col0 = blockIdx.x * BN;
    const int tx = tid & 15;
    const int ty = tid >> 4;

    const int a_r = tid >> 2;
    const int a_c = (tid & 3) << 2;
    const int b_r = tid >> 4;
    const int b_c = (tid & 15) << 2;

    double acc[4][4] = {};

    for (int k0 = 0; k0 < K; k0 += BK) {
        const float4 av = *(const float4*)(A + (size_t)(row0 + a_r) * K + (k0 + a_c));
        As[a_c + 0][a_r] = av.x;
        As[a_c + 1][a_r] = av.y;
        As[a_c + 2][a_r] = av.z;
        As[a_c + 3][a_r] = av.w;

        const float4 bv = *(const float4*)(W + (size_t)(k0 + b_r) * N + (col0 + b_c));
        *(float4*)&Bs[b_r][b_c] = bv;

        __syncthreads();
        #pragma unroll
        for (int kk = 0; kk < BK; ++kk) {
            const float4 a = *(const float4*)&As[kk][ty << 2];
            const float4 b = *(const float4*)&Bs[kk][tx << 2];
            const double ar[4] = {(double)a.x, (double)a.y, (double)a.z, (double)a.w};
            const double br[4] = {(double)b.x, (double)b.y, (double)b.z, (double)b.w};
            #pragma unroll
            for (int i = 0; i < 4; ++i)
                #pragma unroll
                for (int j = 0; j < 4; ++j)
                    acc[i][j] = fma(ar[i], br[j], acc[i][j]);
        }
        __syncthreads();
    }

    #pragma unroll
    for (int i = 0; i < 4; ++i) {
        const int r = row0 + (ty << 2) + i;
        #pragma unroll
        for (int j = 0; j < 4; ++j) {
            const int c = col0 + (tx << 2) + j;
            double v = acc[i][j] + (double)bias[c];
            if (ACT == 1) v = fmax(v, 0.0);
            C[(size_t)r * N + c] = (float)v;
        }
    }
}

// ---------------- residual VQ, f64 distances ----------------
// One wave per row; 4 rows per 256-thread block. encq: in = enc [B,256],
// out = quantized (in-place). idx written as float.
__global__ __launch_bounds__(256)
void vq_kernel(float* __restrict__ encq,
               const float* __restrict__ cb0, const float* __restrict__ cb1,
               float* __restrict__ idx_out, float* __restrict__ commit_acc)
{
    __shared__ float rbuf[4][D_LAT];
    __shared__ float csum[4];
    const int wave = threadIdx.x >> 6;
    const int lane = threadIdx.x & 63;
    const int row  = (blockIdx.x << 2) + wave;

    const float4 e = *(const float4*)(encq + (size_t)row * D_LAT + (lane << 2));
    *(float4*)&rbuf[wave][lane << 2] = e;
    __syncthreads();

    float commit = 0.f;
    float4 qacc = make_float4(0.f, 0.f, 0.f, 0.f);
    int indices[2];

    #pragma unroll
    for (int q = 0; q < 2; ++q) {
        const float* __restrict__ cb = (q == 0) ? cb0 : cb1;
        // offset-free discriminant s = sum_k c_k*(c_k - 2 r_k), f64:
        // argmin(s) == argmin(||r||^2 + s) = argmin(||r-c||^2), noise ~1e-15.
        double best = 1e300;
        int bidx = 0;
        for (int j = 0; j < 4; ++j) {
            const int code = (j << 6) + lane;
            const float* __restrict__ cp = cb + (size_t)code * D_LAT;
            double d = 0.0;
            #pragma unroll 4
            for (int t = 0; t < 64; ++t) {
                const float4 c = *(const float4*)(cp + (t << 2));
                const float4 r = *(const float4*)&rbuf[wave][t << 2];
                d = fma((double)c.x, (double)c.x - 2.0 * (double)r.x, d);
                d = fma((double)c.y, (double)c.y - 2.0 * (double)r.y, d);
                d = fma((double)c.z, (double)c.z - 2.0 * (double)r.z, d);
                d = fma((double)c.w, (double)c.w - 2.0 * (double)r.w, d);
            }
            if (d < best) { best = d; bidx = code; }   // j ascending: first-min per lane
        }
        // cross-lane argmin; tie -> lower index (matches argmin first-occurrence)
        #pragma unroll
        for (int off = 32; off > 0; off >>= 1) {
            const double od = __shfl_xor(best, off, 64);
            const int    oi = __shfl_xor(bidx, off, 64);
            if (od < best || (od == best && oi < bidx)) { best = od; bidx = oi; }
        }
        indices[q] = bidx;

        // gather chosen code, accumulate quantized, update residual, commit partial
        const float4 qv = *(const float4*)(cb + (size_t)bidx * D_LAT + (lane << 2));
        qacc.x += qv.x; qacc.y += qv.y; qacc.z += qv.z; qacc.w += qv.w;
        __syncthreads();
        float4 r = *(const float4*)&rbuf[wave][lane << 2];
        r.x -= qv.x; r.y -= qv.y; r.z -= qv.z; r.w -= qv.w;
        *(float4*)&rbuf[wave][lane << 2] = r;
        commit = fmaf(r.x, r.x, commit); commit = fmaf(r.y, r.y, commit);
        commit = fmaf(r.z, r.z, commit); commit = fmaf(r.w, r.w, commit);
        __syncthreads();
    }

    *(float4*)(encq + (size_t)row * D_LAT + (lane << 2)) = qacc;
    if (lane == 0) {
        idx_out[(size_t)row * 2 + 0] = (float)indices[0];
        idx_out[(size_t)row * 2 + 1] = (float)indices[1];
    }
    // commit currently holds this lane's partial sum over both layers
    #pragma unroll
    for (int off = 32; off > 0; off >>= 1)
        commit += __shfl_xor(commit, off, 64);
    if (lane == 0) csum[wave] = commit;
    __syncthreads();
    if (threadIdx.x == 0)
        atomicAdd(commit_acc, csum[0] + csum[1] + csum[2] + csum[3]);
}

__global__ void finalize_kernel(const float* __restrict__ acc, float* __restrict__ out_loss)
{
    const float recon_loss  = acc[0] / (float)((size_t)B_ROWS * D_IN);
    const float commit_loss = 0.25f * acc[1] / (float)((size_t)B_ROWS * D_LAT);
    *out_loss = recon_loss + commit_loss;
}

extern "C" void kernel_launch(void* const* d_in, const int* in_sizes, int n_in,
                              void* d_out, int out_size, void* d_ws, size_t ws_size,
                              hipStream_t stream)
{
    const float* x   = (const float*)d_in[0];
    const float* We1 = (const float*)d_in[1];
    const float* be1 = (const float*)d_in[2];
    const float* We2 = (const float*)d_in[3];
    const float* be2 = (const float*)d_in[4];
    const float* cb0 = (const float*)d_in[5];
    const float* cb1 = (const float*)d_in[6];
    const float* Wd1 = (const float*)d_in[7];
    const float* bd1 = (const float*)d_in[8];
    const float* Wd2 = (const float*)d_in[9];
    const float* bd2 = (const float*)d_in[10];

    float* out      = (float*)d_out;
    float* recon    = out;                                   // B*784
    float* idx_out  = out + (size_t)B_ROWS * D_IN;           // B*2 (as float)
    float* loss_out = idx_out + (size_t)B_ROWS * 2;          // 1

    float* h   = (float*)d_ws;                               // B*512
    float* acc = (float*)((char*)d_ws + (size_t)B_ROWS * D_HID * sizeof(float));

    // enc/quantized temporarily live in the recon region of d_out
    float* encq = recon;

    hipMemsetAsync(acc, 0, 2 * sizeof(float), stream);

    const dim3 blk(256);
    // encoder 1 (f64 acc): relu(x @ We1 + be1) -> h
    gemm_f64_kernel<1><<<dim3(D_HID / BN, B_ROWS / BM), blk, 0, stream>>>(
        x, We1, be1, h, B_ROWS, D_HID, D_IN);
    // encoder 2 (f64 acc): h @ We2 + be2 -> enc
    gemm_f64_kernel<0><<<dim3(D_LAT / BN, B_ROWS / BM), blk, 0, stream>>>(
        h, We2, be2, encq, B_ROWS, D_LAT, D_HID);
    // residual VQ (f64 distances), indices, commit partials
    vq_kernel<<<dim3(B_ROWS / 4), blk, 0, stream>>>(encq, cb0, cb1, idx_out, acc + 1);
    // decoder 1 (f32): relu(quantized @ Wd1 + bd1) -> h
    gemm_kernel<1, false><<<dim3(D_HID / BN, B_ROWS / BM), blk, 0, stream>>>(
        encq, Wd1, bd1, h, nullptr, nullptr, B_ROWS, D_HID, D_LAT);
    // decoder 2 (f32): tanh(h @ Wd2 + bd2) -> recon, fused MSE partials
    gemm_kernel<2, true><<<dim3((D_IN + BN - 1) / BN, B_ROWS / BM), blk, 0, stream>>>(
        h, Wd2, bd2, recon, x, acc + 0, B_ROWS, D_IN, D_HID);
    finalize_kernel<<<1, 1, 0, stream>>>(acc, loss_out);
}

// Round 3
// 3565.726 us; speedup vs baseline: 1.9625x; 1.9625x over previous
//
#include <hip/hip_runtime.h>
#include <math.h>

#define B_ROWS 65536
#define D_IN   784
#define D_HID  512
#define D_LAT  256
#define N_CODES 256

#define BM 64
#define BN 64
#define BK 16

// ---------- u64 argmin key: ordered f64 bits, low 8 bits = code ----------
// Monotonic in d; truncating mantissa low bits (~1e-13 rel) is far below the
// best/2nd-best gap (~0.04). Ties -> lower code wins (matches jnp.argmin).
__device__ __forceinline__ unsigned long long enc_key(double d, int code) {
    unsigned long long u = (unsigned long long)__double_as_longlong(d);
    u = (u & 0x8000000000000000ull) ? ~u : (u | 0x8000000000000000ull);
    return (u & ~0xFFull) | (unsigned long long)code;
}
__device__ __forceinline__ double dec_key(unsigned long long k) {
    k &= ~0xFFull;
    k = (k & 0x8000000000000000ull) ? (k ^ 0x8000000000000000ull) : ~k;
    return __longlong_as_double((long long)k);
}

// ---------------- f32 GEMM (decoder path) ----------------
template<int ACT, bool FUSE_LOSS>   // ACT: 0=none,1=relu,2=tanh
__global__ __launch_bounds__(256)
void gemm_kernel(const float* __restrict__ A, const float* __restrict__ W,
                 const float* __restrict__ bias, float* __restrict__ C,
                 const float* __restrict__ X, float* __restrict__ loss_acc,
                 int M, int N, int K)
{
    __shared__ float As[BK][BM + 4];
    __shared__ float Bs[BK][BN + 4];
    __shared__ float wsum[4];

    const int tid  = threadIdx.x;
    const int row0 = blockIdx.y * BM;
    const int col0 = blockIdx.x * BN;
    const int tx = tid & 15;
    const int ty = tid >> 4;
    const int a_r = tid >> 2;
    const int a_c = (tid & 3) << 2;
    const int b_r = tid >> 4;
    const int b_c = (tid & 15) << 2;

    float acc[4][4] = {};

    for (int k0 = 0; k0 < K; k0 += BK) {
        const float4 av = *(const float4*)(A + (size_t)(row0 + a_r) * K + (k0 + a_c));
        As[a_c + 0][a_r] = av.x;
        As[a_c + 1][a_r] = av.y;
        As[a_c + 2][a_r] = av.z;
        As[a_c + 3][a_r] = av.w;

        const int gc = col0 + b_c;
        float4 bv;
        if (gc + 3 < N) {
            bv = *(const float4*)(W + (size_t)(k0 + b_r) * N + gc);
        } else {
            bv.x = (gc + 0 < N) ? W[(size_t)(k0 + b_r) * N + gc + 0] : 0.f;
            bv.y = (gc + 1 < N) ? W[(size_t)(k0 + b_r) * N + gc + 1] : 0.f;
            bv.z = (gc + 2 < N) ? W[(size_t)(k0 + b_r) * N + gc + 2] : 0.f;
            bv.w = (gc + 3 < N) ? W[(size_t)(k0 + b_r) * N + gc + 3] : 0.f;
        }
        *(float4*)&Bs[b_r][b_c] = bv;

        __syncthreads();
        #pragma unroll
        for (int kk = 0; kk < BK; ++kk) {
            const float4 a = *(const float4*)&As[kk][ty << 2];
            const float4 b = *(const float4*)&Bs[kk][tx << 2];
            const float ar[4] = {a.x, a.y, a.z, a.w};
            const float br[4] = {b.x, b.y, b.z, b.w};
            #pragma unroll
            for (int i = 0; i < 4; ++i)
                #pragma unroll
                for (int j = 0; j < 4; ++j)
                    acc[i][j] = fmaf(ar[i], br[j], acc[i][j]);
        }
        __syncthreads();
    }

    float lsum = 0.f;
    #pragma unroll
    for (int i = 0; i < 4; ++i) {
        const int r = row0 + (ty << 2) + i;
        #pragma unroll
        for (int j = 0; j < 4; ++j) {
            const int c = col0 + (tx << 2) + j;
            if (c < N) {
                float v = acc[i][j] + bias[c];
                if (ACT == 1) v = fmaxf(v, 0.f);
                if (ACT == 2) v = tanhf(v);
                C[(size_t)r * N + c] = v;
                if (FUSE_LOSS) {
                    const float d = v - X[(size_t)r * N + c];
                    lsum = fmaf(d, d, lsum);
                }
            }
        }
    }

    if (FUSE_LOSS) {
        #pragma unroll
        for (int off = 32; off > 0; off >>= 1)
            lsum += __shfl_xor(lsum, off, 64);
        if ((tid & 63) == 0) wsum[tid >> 6] = lsum;
        __syncthreads();
        if (tid == 0)
            atomicAdd(loss_acc, wsum[0] + wsum[1] + wsum[2] + wsum[3]);
    }
}

// ---------------- f64-accumulate GEMM (encoder path) ----------------
template<int ACT>
__global__ __launch_bounds__(256)
void gemm_f64_kernel(const float* __restrict__ A, const float* __restrict__ W,
                     const float* __restrict__ bias, float* __restrict__ C,
                     int M, int N, int K)
{
    __shared__ float As[BK][BM + 4];
    __shared__ float Bs[BK][BN + 4];

    const int tid  = threadIdx.x;
    const int row0 = blockIdx.y * BM;
    const int col0 = blockIdx.x * BN;
    const int tx = tid & 15;
    const int ty = tid >> 4;
    const int a_r = tid >> 2;
    const int a_c = (tid & 3) << 2;
    const int b_r = tid >> 4;
    const int b_c = (tid & 15) << 2;

    double acc[4][4] = {};

    for (int k0 = 0; k0 < K; k0 += BK) {
        const float4 av = *(const float4*)(A + (size_t)(row0 + a_r) * K + (k0 + a_c));
        As[a_c + 0][a_r] = av.x;
        As[a_c + 1][a_r] = av.y;
        As[a_c + 2][a_r] = av.z;
        As[a_c + 3][a_r] = av.w;

        const float4 bv = *(const float4*)(W + (size_t)(k0 + b_r) * N + (col0 + b_c));
        *(float4*)&Bs[b_r][b_c] = bv;

        __syncthreads();
        #pragma unroll
        for (int kk = 0; kk < BK; ++kk) {
            const float4 a = *(const float4*)&As[kk][ty << 2];
            const float4 b = *(const float4*)&Bs[kk][tx << 2];
            const double ar[4] = {(double)a.x, (double)a.y, (double)a.z, (double)a.w};
            const double br[4] = {(double)b.x, (double)b.y, (double)b.z, (double)b.w};
            #pragma unroll
            for (int i = 0; i < 4; ++i)
                #pragma unroll
                for (int j = 0; j < 4; ++j)
                    acc[i][j] = fma(ar[i], br[j], acc[i][j]);
        }
        __syncthreads();
    }

    #pragma unroll
    for (int i = 0; i < 4; ++i) {
        const int r = row0 + (ty << 2) + i;
        #pragma unroll
        for (int j = 0; j < 4; ++j) {
            const int c = col0 + (tx << 2) + j;
            double v = acc[i][j] + (double)bias[c];
            if (ACT == 1) v = fmax(v, 0.0);
            C[(size_t)r * N + c] = (float)v;
        }
    }
}

// ---------------- codebook squared norms (f64) ----------------
__global__ void cnorm_kernel(const float* __restrict__ cb0, const float* __restrict__ cb1,
                             double* __restrict__ cn0, double* __restrict__ cn1)
{
    const float* cb = blockIdx.x ? cb1 : cb0;
    double* cn      = blockIdx.x ? cn1 : cn0;
    const int j = threadIdx.x;
    const float* row = cb + (size_t)j * D_LAT;
    double s = 0.0;
    #pragma unroll 8
    for (int t = 0; t < 64; ++t) {
        const float4 c = *(const float4*)(row + (t << 2));
        s = fma((double)c.x, (double)c.x, s);
        s = fma((double)c.y, (double)c.y, s);
        s = fma((double)c.z, (double)c.z, s);
        s = fma((double)c.w, (double)c.w, s);
    }
    cn[j] = s;
}

// ---------------- VQ distance GEMM pass (f64) ----------------
// Computes dot = r @ cb^T tile-wise; epilogue turns it into the discriminant
// d = ||c||^2 - 2*dot, encodes (d,code) keys and atomicMin's per row.
// SUB: A-row = enc[row] - cbA[idx0[row]] (residual for stage 2), idx0 from key_in.
template<bool SUB>
__global__ __launch_bounds__(256)
void vq_dots_kernel(const float* __restrict__ enc, const float* __restrict__ cbA,
                    const unsigned long long* __restrict__ key_in,
                    const float* __restrict__ cb, const double* __restrict__ cnorm,
                    unsigned long long* __restrict__ key_out)
{
    __shared__ float As[BK][BM + 4];
    __shared__ float Bs[BK][BN + 4];

    const int tid   = threadIdx.x;
    const int row0  = blockIdx.y * BM;
    const int code0 = blockIdx.x * BN;
    const int tx = tid & 15;
    const int ty = tid >> 4;
    const int a_r = tid >> 2;
    const int a_c = (tid & 3) << 2;

    double acc[4][4] = {};

    int sub_idx = 0;
    if (SUB)
        sub_idx = (int)(key_in[row0 + a_r] & 0xFFull);

    for (int k0 = 0; k0 < D_LAT; k0 += BK) {
        float4 av = *(const float4*)(enc + (size_t)(row0 + a_r) * D_LAT + (k0 + a_c));
        if (SUB) {
            const float4 qv = *(const float4*)(cbA + (size_t)sub_idx * D_LAT + (k0 + a_c));
            av.x -= qv.x; av.y -= qv.y; av.z -= qv.z; av.w -= qv.w;
        }
        As[a_c + 0][a_r] = av.x;
        As[a_c + 1][a_r] = av.y;
        As[a_c + 2][a_r] = av.z;
        As[a_c + 3][a_r] = av.w;

        // codebook tile: codes are rows of cb -> transpose into Bs[k][code]
        const float4 bv = *(const float4*)(cb + (size_t)(code0 + a_r) * D_LAT + (k0 + a_c));
        Bs[a_c + 0][a_r] = bv.x;
        Bs[a_c + 1][a_r] = bv.y;
        Bs[a_c + 2][a_r] = bv.z;
        Bs[a_c + 3][a_r] = bv.w;

        __syncthreads();
        #pragma unroll
        for (int kk = 0; kk < BK; ++kk) {
            const float4 a = *(const float4*)&As[kk][ty << 2];
            const float4 b = *(const float4*)&Bs[kk][tx << 2];
            const double ar[4] = {(double)a.x, (double)a.y, (double)a.z, (double)a.w};
            const double br[4] = {(double)b.x, (double)b.y, (double)b.z, (double)b.w};
            #pragma unroll
            for (int i = 0; i < 4; ++i)
                #pragma unroll
                for (int j = 0; j < 4; ++j)
                    acc[i][j] = fma(ar[i], br[j], acc[i][j]);
        }
        __syncthreads();
    }

    // epilogue: per-thread min over 4 codes, butterfly-min across the 16 tx
    // lanes sharing each row (they live in the same wave), then atomicMin.
    unsigned long long kmin[4];
    #pragma unroll
    for (int i = 0; i < 4; ++i) {
        kmin[i] = 0xFFFFFFFFFFFFFFFFull;
        #pragma unroll
        for (int j = 0; j < 4; ++j) {
            const int code = code0 + (tx << 2) + j;
            const double d = cnorm[code] - 2.0 * acc[i][j];
            const unsigned long long k = enc_key(d, code);
            if (k < kmin[i]) kmin[i] = k;
        }
    }
    #pragma unroll
    for (int off = 1; off < 16; off <<= 1) {
        #pragma unroll
        for (int i = 0; i < 4; ++i) {
            const unsigned long long o = __shfl_xor(kmin[i], off, 64);
            if (o < kmin[i]) kmin[i] = o;
        }
    }
    if (tx == 0) {
        #pragma unroll
        for (int i = 0; i < 4; ++i)
            atomicMin(key_out + row0 + (ty << 2) + i, kmin[i]);
    }
}

// ---------------- VQ finalize: indices, commit, quantized ----------------
// encq in: enc rows; out: quantized = cb0[i0] + cb1[i1] (in place).
// commit_row = 2*(||r0||^2 + d0) + d1  (since ||r1||^2 = commit0).
__global__ __launch_bounds__(256)
void vq_finalize_kernel(float* __restrict__ encq,
                        const float* __restrict__ cb0, const float* __restrict__ cb1,
                        const unsigned long long* __restrict__ key0,
                        const unsigned long long* __restrict__ key1,
                        float* __restrict__ idx_out, float* __restrict__ commit_acc)
{
    __shared__ float csum[4];
    const int wave = threadIdx.x >> 6;
    const int lane = threadIdx.x & 63;
    const int row  = (blockIdx.x << 2) + wave;

    const unsigned long long k0 = key0[row];
    const unsigned long long k1 = key1[row];
    const int i0 = (int)(k0 & 0xFFull);
    const int i1 = (int)(k1 & 0xFFull);

    const float4 e = *(const float4*)(encq + (size_t)row * D_LAT + (lane << 2));
    float nrm = 0.f;
    nrm = fmaf(e.x, e.x, nrm); nrm = fmaf(e.y, e.y, nrm);
    nrm = fmaf(e.z, e.z, nrm); nrm = fmaf(e.w, e.w, nrm);
    #pragma unroll
    for (int off = 32; off > 0; off >>= 1)
        nrm += __shfl_xor(nrm, off, 64);

    const float4 q0 = *(const float4*)(cb0 + (size_t)i0 * D_LAT + (lane << 2));
    const float4 q1 = *(const float4*)(cb1 + (size_t)i1 * D_LAT + (lane << 2));
    const float4 q = make_float4(q0.x + q1.x, q0.y + q1.y, q0.z + q1.z, q0.w + q1.w);
    *(float4*)(encq + (size_t)row * D_LAT + (lane << 2)) = q;

    if (lane == 0) {
        idx_out[(size_t)row * 2 + 0] = (float)i0;
        idx_out[(size_t)row * 2 + 1] = (float)i1;
        const float d0 = (float)dec_key(k0);
        const float d1 = (float)dec_key(k1);
        csum[wave] = 2.f * (nrm + d0) + d1;
    }
    __syncthreads();
    if (threadIdx.x == 0)
        atomicAdd(commit_acc, csum[0] + csum[1] + csum[2] + csum[3]);
}

__global__ void finalize_kernel(const float* __restrict__ acc, float* __restrict__ out_loss)
{
    const float recon_loss  = acc[0] / (float)((size_t)B_ROWS * D_IN);
    const float commit_loss = 0.25f * acc[1] / (float)((size_t)B_ROWS * D_LAT);
    *out_loss = recon_loss + commit_loss;
}

extern "C" void kernel_launch(void* const* d_in, const int* in_sizes, int n_in,
                              void* d_out, int out_size, void* d_ws, size_t ws_size,
                              hipStream_t stream)
{
    const float* x   = (const float*)d_in[0];
    const float* We1 = (const float*)d_in[1];
    const float* be1 = (const float*)d_in[2];
    const float* We2 = (const float*)d_in[3];
    const float* be2 = (const float*)d_in[4];
    const float* cb0 = (const float*)d_in[5];
    const float* cb1 = (const float*)d_in[6];
    const float* Wd1 = (const float*)d_in[7];
    const float* bd1 = (const float*)d_in[8];
    const float* Wd2 = (const float*)d_in[9];
    const float* bd2 = (const float*)d_in[10];

    float* out      = (float*)d_out;
    float* recon    = out;                                   // B*784
    float* idx_out  = out + (size_t)B_ROWS * D_IN;           // B*2 (as float)
    float* loss_out = idx_out + (size_t)B_ROWS * 2;          // 1

    // ws layout
    char* w = (char*)d_ws;
    float* h = (float*)w;                    w += (size_t)B_ROWS * D_HID * sizeof(float);
    float* acc = (float*)w;                  w += 16;
    unsigned long long* key0 = (unsigned long long*)w;  w += (size_t)B_ROWS * 8;
    unsigned long long* key1 = (unsigned long long*)w;  w += (size_t)B_ROWS * 8;
    double* cn0 = (double*)w;                w += N_CODES * sizeof(double);
    double* cn1 = (double*)w;                w += N_CODES * sizeof(double);

    // enc/quantized live in the recon region of d_out (dead before recon write)
    float* encq = recon;

    hipMemsetAsync(acc, 0, 2 * sizeof(float), stream);
    hipMemsetAsync(key0, 0xFF, (size_t)B_ROWS * 16, stream);   // key0 + key1

    const dim3 blk(256);
    // codebook norms (f64)
    cnorm_kernel<<<dim3(2), blk, 0, stream>>>(cb0, cb1, cn0, cn1);
    // encoder 1 (f64 acc): relu(x @ We1 + be1) -> h
    gemm_f64_kernel<1><<<dim3(D_HID / BN, B_ROWS / BM), blk, 0, stream>>>(
        x, We1, be1, h, B_ROWS, D_HID, D_IN);
    // encoder 2 (f64 acc): h @ We2 + be2 -> enc
    gemm_f64_kernel<0><<<dim3(D_LAT / BN, B_ROWS / BM), blk, 0, stream>>>(
        h, We2, be2, encq, B_ROWS, D_LAT, D_HID);
    // VQ stage 1: distances to cb0, per-row argmin via u64 atomicMin
    vq_dots_kernel<false><<<dim3(N_CODES / BN, B_ROWS / BM), blk, 0, stream>>>(
        encq, nullptr, nullptr, cb0, cn0, key0);
    // VQ stage 2: residual (enc - cb0[i0]) vs cb1
    vq_dots_kernel<true><<<dim3(N_CODES / BN, B_ROWS / BM), blk, 0, stream>>>(
        encq, cb0, key0, cb1, cn1, key1);
    // finalize: indices, commit partials, quantized (in place)
    vq_finalize_kernel<<<dim3(B_ROWS / 4), blk, 0, stream>>>(
        encq, cb0, cb1, key0, key1, idx_out, acc + 1);
    // decoder 1 (f32): relu(quantized @ Wd1 + bd1) -> h
    gemm_kernel<1, false><<<dim3(D_HID / BN, B_ROWS / BM), blk, 0, stream>>>(
        encq, Wd1, bd1, h, nullptr, nullptr, B_ROWS, D_HID, D_LAT);
    // decoder 2 (f32): tanh(h @ Wd2 + bd2) -> recon, fused MSE partials
    gemm_kernel<2, true><<<dim3((D_IN + BN - 1) / BN, B_ROWS / BM), blk, 0, stream>>>(
        h, Wd2, bd2, recon, x, acc + 0, B_ROWS, D_IN, D_HID);
    finalize_kernel<<<1, 1, 0, stream>>>(acc, loss_out);
}